// Round 7
// baseline (145.224 us; speedup 1.0000x reference)
//
#include <hip/hip_runtime.h>
#include <hip/hip_bf16.h>

// BalancedBCE: single-pass fused kernel.
// bce(x,t) = max(x,0) - x*t + log1p(exp(-|x|)), t in {0,1} exactly.
// loss = sum_b (1-tmean_b)*pos_bce_b / pos_cnt + sum_b tmean_b*neg_bce_b / neg_cnt
// Single pass accumulating (pos_bce_sum, neg_bce_sum, pos_cnt) per sample.
//
// R6 post-mortem: VGPR-return loads cap at ~3.3 TB/s effective regardless of
// occupancy (36->60%) or software batch depth (4->16: compiler caps live
// load-results, VGPR=36). Harness fills (no return path) hit 6.5 TB/s.
// R7: global_load_lds DMA staging — fire-and-forget, no VGPR reservation,
// wave-private double-buffered LDS (no __syncthreads -> no vmcnt(0) drain),
// explicit s_waitcnt vmcnt(4) pipelining. 8 x 1KB DMAs in flight per wave.

typedef float v4f __attribute__((ext_vector_type(4)));

#define S_ELEMS (512 * 512)      // per-sample element count (C=1)
#define KPB 16                   // blocks per sample -> 1024 blocks
#define BQ (S_ELEMS / 4)         // float4s per sample = 65536
#define PBQ (BQ / KPB)           // float4s per block  = 4096
#define TPB 256
#define WPB 4                    // waves per block
#define WF4 (PBQ / WPB)          // float4s per wave = 1024
#define LPS 2                    // DMA loads per stream per stage
#define STAGE_F4 (LPS * 64)      // float4s per wave-stage = 128
#define STAGES (WF4 / STAGE_F4)  // 8

// s_waitcnt imm (gfx9 encoding): vmcnt[3:0]|expcnt[6:4]|lgkmcnt[11:8]|vmcnt[5:4]@14
#define WAITCNT_VM4 (4 | (7 << 4) | (15 << 8))   // vmcnt(4), others free
#define WAITCNT_VM0 (0 | (7 << 4) | (15 << 8))   // vmcnt(0), others free
#define WAITCNT_LGKM0 (15 | (7 << 4) | (0 << 8) | (3 << 14))  // lgkmcnt(0)

__device__ __forceinline__ void dma16(const v4f* g, v4f* l) {
  __builtin_amdgcn_global_load_lds(
      (const __attribute__((address_space(1))) void*)g,
      (__attribute__((address_space(3))) void*)l, 16, 0, 0);
}

__global__ __launch_bounds__(TPB) void bce_partial(
    const v4f* __restrict__ x4, const v4f* __restrict__ t4,
    float* __restrict__ part) {
  // [wave][buf][stream][128 f4] = 32 KB -> 4+ blocks/CU
  __shared__ v4f stage[WPB][2][2][STAGE_F4];

  const int blk = blockIdx.x;
  const int b = blk / KPB;
  const int k = blk % KPB;
  const int wave = threadIdx.x >> 6;
  const int lane = threadIdx.x & 63;
  const long wbase = (long)b * BQ + (long)k * PBQ + (long)wave * WF4;

  // issue stage 0 into buf 0: lane i's 16B lands at ldsbase + i*16
#pragma unroll
  for (int j = 0; j < LPS; ++j) {
    dma16(&x4[wbase + j * 64 + lane], &stage[wave][0][0][j * 64]);
    dma16(&t4[wbase + j * 64 + lane], &stage[wave][0][1][j * 64]);
  }

  float pos_s = 0.f, neg_s = 0.f, pos_c = 0.f;

#pragma unroll
  for (int s = 0; s < STAGES; ++s) {
    const int buf = s & 1;
    if (s + 1 < STAGES) {
      // prior ds_reads (which used buf^1) must be done before overwriting it
      __builtin_amdgcn_s_waitcnt(WAITCNT_LGKM0);
      __asm__ volatile("" ::: "memory");
      const long nb = wbase + (long)(s + 1) * STAGE_F4;
#pragma unroll
      for (int j = 0; j < LPS; ++j) {
        dma16(&x4[nb + j * 64 + lane], &stage[wave][buf ^ 1][0][j * 64]);
        dma16(&t4[nb + j * 64 + lane], &stage[wave][buf ^ 1][1][j * 64]);
      }
      __builtin_amdgcn_s_waitcnt(WAITCNT_VM4);  // stage s's 4 DMAs landed
    } else {
      __builtin_amdgcn_s_waitcnt(WAITCNT_VM0);
    }
    __asm__ volatile("" ::: "memory");

#pragma unroll
    for (int j = 0; j < LPS; ++j) {
      const v4f xv = stage[wave][buf][0][j * 64 + lane];
      const v4f tv = stage[wave][buf][1][j * 64 + lane];
#pragma unroll
      for (int c = 0; c < 4; ++c) {
        const float xc = xv[c];
        const float tc = tv[c];  // exactly 0.0 or 1.0
        const float ax = fabsf(xc);
        const float l1p = __logf(1.f + __expf(-ax));  // log1p(exp(-|x|))
        const float common = fmaxf(xc, 0.f) + l1p;    // bce at t=0
        pos_s = fmaf(tc, common - xc, pos_s);         // bce at t=1 = common-x
        neg_s = fmaf(1.f - tc, common, neg_s);
        pos_c += tc;
      }
    }
  }

  // wave (64-lane) shuffle reduction
#pragma unroll
  for (int off = 32; off > 0; off >>= 1) {
    pos_s += __shfl_down(pos_s, off, 64);
    neg_s += __shfl_down(neg_s, off, 64);
    pos_c += __shfl_down(pos_c, off, 64);
  }

  __shared__ float sm[3][WPB];
  if (lane == 0) {
    sm[0][wave] = pos_s;
    sm[1][wave] = neg_s;
    sm[2][wave] = pos_c;
  }
  __syncthreads();
  if (threadIdx.x == 0) {
    float p = 0.f, n = 0.f, c = 0.f;
#pragma unroll
    for (int w = 0; w < WPB; ++w) {
      p += sm[0][w];
      n += sm[1][w];
      c += sm[2][w];
    }
    part[blk * 3 + 0] = p;
    part[blk * 3 + 1] = n;
    part[blk * 3 + 2] = c;
  }
}

// One wave: lane b handles sample b (B = 64), summing KPB partials each.
__global__ __launch_bounds__(64) void bce_final(
    const float* __restrict__ part, float* __restrict__ out, int B) {
  const int b = threadIdx.x;
  float p = 0.f, n = 0.f, c = 0.f;
  if (b < B) {
#pragma unroll
    for (int k = 0; k < KPB; ++k) {
      const int blk = b * KPB + k;
      p += part[blk * 3 + 0];
      n += part[blk * 3 + 1];
      c += part[blk * 3 + 2];
    }
  }
  const float tmean = c * (1.f / (float)S_ELEMS);
  float wp = (1.f - tmean) * p;
  float wn = tmean * n;
  float ct = c;
#pragma unroll
  for (int off = 32; off > 0; off >>= 1) {
    wp += __shfl_down(wp, off, 64);
    wn += __shfl_down(wn, off, 64);
    ct += __shfl_down(ct, off, 64);
  }
  if (b == 0) {
    const float pos_cnt = ct;
    const float neg_cnt = (float)B * (float)S_ELEMS - pos_cnt;
    out[0] = wp / pos_cnt + wn / neg_cnt;
  }
}

extern "C" void kernel_launch(void* const* d_in, const int* in_sizes, int n_in,
                              void* d_out, int out_size, void* d_ws, size_t ws_size,
                              hipStream_t stream) {
  const v4f* x4 = (const v4f*)d_in[0];
  const v4f* t4 = (const v4f*)d_in[1];
  float* out = (float*)d_out;
  float* part = (float*)d_ws;  // nblocks * 3 floats

  const int total = in_sizes[0];           // 16777216
  const int B = total / S_ELEMS;           // 64
  const int nblocks = B * KPB;             // 1024

  bce_partial<<<nblocks, TPB, 0, stream>>>(x4, t4, part);
  bce_final<<<1, 64, 0, stream>>>(part, out, B);
}

// Round 8
// 139.564 us; speedup vs baseline: 1.0406x; 1.0406x over previous
//
#include <hip/hip_runtime.h>
#include <hip/hip_bf16.h>

// BalancedBCE: single-pass fused kernel.
// bce(x,t) = max(x,0) - x*t + log1p(exp(-|x|)), t in {0,1} exactly.
// loss = sum_b (1-tmean_b)*pos_bce_b / pos_cnt + sum_b tmean_b*neg_bce_b / neg_cnt
// Single pass accumulating (pos_bce_sum, neg_bce_sum, pos_cnt) per sample,
// then a tiny finalize kernel applies the count-derived weights.
//
// R7 post-mortem / final config: six mechanisms (register-return plain/nt,
// 4/8/16-deep batches, 27-60% occupancy, LDS-DMA staging) all converge to
// 38-47 us => device read-return path saturates ~3.4 TB/s (the 6.3 TB/s
// "achievable" figure is a copy counting read+write). Only nontemporal moved
// the needle (-5 us). This is the best measured variant (R4, total 139.6 us):
// nt loads, 8 x 16B in flight, KPB=64 -> 4096 blocks. At the read roofline;
// the other ~100 us of the timed region is harness restore/poison traffic.

typedef float v4f __attribute__((ext_vector_type(4)));

#define S_ELEMS (512 * 512)        // per-sample element count (C=1)
#define KPB 64                     // blocks per sample
#define BQ (S_ELEMS / 4)           // float4s per sample = 65536
#define PBQ (BQ / KPB)             // float4s per block  = 1024
#define TPB 256                    // threads per block
#define ITERS (PBQ / TPB)          // 4 float4 iterations per thread

__global__ __launch_bounds__(TPB, 8) void bce_partial(
    const v4f* __restrict__ x4, const v4f* __restrict__ t4,
    float* __restrict__ part) {
  const int blk = blockIdx.x;
  const int b = blk >> 6;          // blk / KPB
  const int k = blk & (KPB - 1);   // blk % KPB
  const long base = (long)b * BQ + (long)k * PBQ + threadIdx.x;

  // Issue ALL loads up front: 8 x 16B = 128 B outstanding per thread.
  v4f xv[ITERS], tv[ITERS];
#pragma unroll
  for (int i = 0; i < ITERS; ++i)
    xv[i] = __builtin_nontemporal_load(&x4[base + (long)i * TPB]);
#pragma unroll
  for (int i = 0; i < ITERS; ++i)
    tv[i] = __builtin_nontemporal_load(&t4[base + (long)i * TPB]);

  float pos_s = 0.f, neg_s = 0.f, pos_c = 0.f;
#pragma unroll
  for (int i = 0; i < ITERS; ++i) {
#pragma unroll
    for (int c = 0; c < 4; ++c) {
      const float xc = xv[i][c];
      const float tc = tv[i][c];  // exactly 0.0 or 1.0
      const float ax = fabsf(xc);
      const float l1p = __logf(1.f + __expf(-ax));  // log1p(exp(-|x|))
      const float common = fmaxf(xc, 0.f) + l1p;    // bce at t=0
      pos_s = fmaf(tc, common - xc, pos_s);         // bce at t=1 = common - x
      neg_s = fmaf(1.f - tc, common, neg_s);
      pos_c += tc;
    }
  }

  // wave (64-lane) shuffle reduction
#pragma unroll
  for (int off = 32; off > 0; off >>= 1) {
    pos_s += __shfl_down(pos_s, off, 64);
    neg_s += __shfl_down(neg_s, off, 64);
    pos_c += __shfl_down(pos_c, off, 64);
  }

  __shared__ float sm[3][TPB / 64];
  const int lane = threadIdx.x & 63;
  const int wave = threadIdx.x >> 6;
  if (lane == 0) {
    sm[0][wave] = pos_s;
    sm[1][wave] = neg_s;
    sm[2][wave] = pos_c;
  }
  __syncthreads();
  if (threadIdx.x == 0) {
    float p = 0.f, n = 0.f, c = 0.f;
#pragma unroll
    for (int w = 0; w < TPB / 64; ++w) {
      p += sm[0][w];
      n += sm[1][w];
      c += sm[2][w];
    }
    part[blk * 3 + 0] = p;
    part[blk * 3 + 1] = n;
    part[blk * 3 + 2] = c;
  }
}

// One wave: lane b handles sample b (B = 64), summing KPB partials each.
__global__ __launch_bounds__(64) void bce_final(
    const float* __restrict__ part, float* __restrict__ out, int B) {
  const int b = threadIdx.x;
  float p = 0.f, n = 0.f, c = 0.f;
  if (b < B) {
#pragma unroll 8
    for (int k = 0; k < KPB; ++k) {
      const int blk = b * KPB + k;
      p += part[blk * 3 + 0];
      n += part[blk * 3 + 1];
      c += part[blk * 3 + 2];
    }
  }
  const float tmean = c * (1.f / (float)S_ELEMS);
  float wp = (1.f - tmean) * p;  // weighted positive bce sum for sample b
  float wn = tmean * n;          // weighted negative bce sum for sample b
  float ct = c;
#pragma unroll
  for (int off = 32; off > 0; off >>= 1) {
    wp += __shfl_down(wp, off, 64);
    wn += __shfl_down(wn, off, 64);
    ct += __shfl_down(ct, off, 64);
  }
  if (b == 0) {
    const float pos_cnt = ct;
    const float neg_cnt = (float)B * (float)S_ELEMS - pos_cnt;
    out[0] = wp / pos_cnt + wn / neg_cnt;
  }
}

extern "C" void kernel_launch(void* const* d_in, const int* in_sizes, int n_in,
                              void* d_out, int out_size, void* d_ws, size_t ws_size,
                              hipStream_t stream) {
  const v4f* x4 = (const v4f*)d_in[0];
  const v4f* t4 = (const v4f*)d_in[1];
  float* out = (float*)d_out;
  float* part = (float*)d_ws;  // nblocks * 3 floats

  const int total = in_sizes[0];           // 16777216
  const int B = total / S_ELEMS;           // 64
  const int nblocks = B * KPB;             // 4096

  bce_partial<<<nblocks, TPB, 0, stream>>>(x4, t4, part);
  bce_final<<<1, 64, 0, stream>>>(part, out, B);
}